// Round 4
// baseline (108.287 us; speedup 1.0000x reference)
//
#include <hip/hip_runtime.h>
#include <math.h>

// Problem constants: bs=32, en=256, dx=512, dz=256, heads=8, dh=32, L=1280.
//
// Mask is block-diagonal eyes: q<256 -> one-hot row; q=256+j -> exactly 4
// nonzeros {q, 512+j, 768+j, 1024+j} = col 256+j of centered state and col j
// of each centered obs. Wk folded into the query side:
//   score[b,j,h,m] = ( sum_e kb_m[e]*(wu[j,h,e]+wv[b,h,e]) + ubk+vbk ) / sqrt(32)
// with kb_m = raw_m - mean_m + pe, via raw/pe/ones dot rows.
//
// ws layout (floats):
//   pe   [32][256]             @ 0
//   u    [256][256]            @ 8192      (Q[256:]@Wq)
//   v    [32][256]             @ 73728     (pe@Wq + bq)
//   wu2  [8][256e][256j]       @ 81920
//   wv   [32][8][256e]         @ 606208
//   ubk  [256][8]              @ 671744
//   vbk  [32][8]               @ 673792
//   a    [32][256][4]          @ 674048    (head-averaged softmax weights)
//   pws  [16jt][32b][2eq][52k][16jl] @ 706816   (851968 floats, partials)
// total ~5.6 MB

// ---------------------------------------------------------------- k_uv
__global__ void k_uv(const float* __restrict__ Q, const float* __restrict__ Wq,
                     const float* __restrict__ bq, const float* __restrict__ bk,
                     float* __restrict__ pe, float* __restrict__ u,
                     float* __restrict__ v, float* __restrict__ ubk,
                     float* __restrict__ vbk) {
  __shared__ float row[256];
  const int f = threadIdx.x;
  const int blk = blockIdx.x;
  float rv;
  if (blk < 256) {
    rv = Q[(256 + blk) * 256 + f];
  } else {
    const int b = blk - 256;
    // sinusoidal PE over the BATCH axis (faithful quirk): pos=b, d_model=256
    const float dv = expf(-9.210340371976184f * (float)((f >> 1) << 1) * (1.0f / 256.0f));
    const float ang = (float)b * dv;
    rv = (f & 1) ? cosf(ang) : sinf(ang);
    pe[b * 256 + f] = rv;
  }
  row[f] = rv;
  __syncthreads();
  float acc = (blk < 256) ? 0.0f : bq[f];
  for (int e = 0; e < 256; ++e) acc += row[e] * Wq[e * 256 + f];
  if (blk < 256) u[blk * 256 + f] = acc;
  else           v[(blk - 256) * 256 + f] = acc;
  float val = acc * bk[f];
  val += __shfl_xor(val, 1);  val += __shfl_xor(val, 2);
  val += __shfl_xor(val, 4);  val += __shfl_xor(val, 8);
  val += __shfl_xor(val, 16);
  if ((f & 31) == 0) {
    const int h = f >> 5;
    if (blk < 256) ubk[blk * 8 + h] = val;
    else           vbk[(blk - 256) * 8 + h] = val;
  }
}

// ---------------------------------------------------------------- k_w
__global__ void k_w(const float* __restrict__ Wk, const float* __restrict__ u,
                    const float* __restrict__ v, float* __restrict__ wu2,
                    float* __restrict__ wv) {
  __shared__ float wrow[256];
  const int e = blockIdx.x;
  const int t = threadIdx.x;
  wrow[t] = Wk[e * 256 + t];
  __syncthreads();
  if (blockIdx.y == 0) {
    const float* ur = u + t * 256;
#pragma unroll
    for (int h = 0; h < 8; ++h) {
      float acc = 0.0f;
#pragma unroll
      for (int d = 0; d < 32; ++d) acc += ur[h * 32 + d] * wrow[h * 32 + d];
      wu2[(h * 256 + e) * 256 + t] = acc;
    }
  } else if (t < 32) {
    const float* vr = v + t * 256;
#pragma unroll
    for (int h = 0; h < 8; ++h) {
      float acc = 0.0f;
#pragma unroll
      for (int d = 0; d < 32; ++d) acc += vr[h * 32 + d] * wrow[h * 32 + d];
      wv[(t * 8 + h) * 256 + e] = acc;
    }
  }
}

// ---------------------------------------------------------------- k_part
// grid (16 jt, 2 eq, 32 b), 256 threads = 4 waves. t = jl(0..15)+16*es(0..15).
// Lane owns j = jt*16+jl, e in [eq*128 + es*8, +8). All global loads are
// 64B-per-16-lane coalesced. Reduce: shfl over lane bits 4,5 then LDS across
// the 4 waves; lanes t<16 write a [52][16] partial record to pws.
__global__ __launch_bounds__(256, 5)
void k_part(const float* __restrict__ state, const float* __restrict__ o0,
            const float* __restrict__ o1, const float* __restrict__ o2,
            const float* __restrict__ pe, const float* __restrict__ wu2,
            const float* __restrict__ wv, float* __restrict__ pws) {
  const int t = threadIdx.x;
  const int jl = t & 15;
  const int es = t >> 4;           // 0..15
  const int jt = blockIdx.x;       // 0..15
  const int eq = blockIdx.y;       // 0..1
  const int b  = blockIdx.z;       // 0..31
  const int j = jt * 16 + jl;

  __shared__ float s_wv[1024];     // [h][128]  (this eq's e-slice)
  __shared__ float s_pe[128];
  __shared__ float s_part[4][16][52];

  for (int i = t; i < 1024; i += 256)
    s_wv[i] = wv[b * 2048 + (i >> 7) * 256 + eq * 128 + (i & 127)];
  if (t < 128) s_pe[t] = pe[b * 256 + eq * 128 + t];
  __syncthreads();

  // acc[h*6+c]: c=0..3 dR(state,o0,o1,o2), c=4 dP(pe), c=5 dO(ones); 48..51 sm
  float acc[52];
#pragma unroll
  for (int k = 0; k < 52; ++k) acc[k] = 0.f;

  const float* ps = state + (size_t)b * 256 * 512 + 256 + j;
  const float* p0 = o0 + (size_t)b * 256 * 256 + j;
  const float* p1 = o1 + (size_t)b * 256 * 256 + j;
  const float* p2 = o2 + (size_t)b * 256 * 256 + j;
  const float* pwu = wu2 + j;      // + (h*256+e)*256

#pragma unroll
  for (int it = 0; it < 8; ++it) {
    const int el = es * 8 + it;    // 0..127 within this eq slice
    const int e = eq * 128 + el;   // global e
    const float s  = ps[(size_t)e * 512];
    const float x0 = p0[(size_t)e * 256];
    const float x1 = p1[(size_t)e * 256];
    const float x2 = p2[(size_t)e * 256];
    const float pv = s_pe[el];
    acc[48] += s; acc[49] += x0; acc[50] += x1; acc[51] += x2;
#pragma unroll
    for (int h = 0; h < 8; ++h) {
      const float w = pwu[(size_t)(h * 256 + e) * 256] + s_wv[h * 128 + el];
      acc[h * 6 + 0] += s * w;  acc[h * 6 + 1] += x0 * w;
      acc[h * 6 + 2] += x1 * w; acc[h * 6 + 3] += x2 * w;
      acc[h * 6 + 4] += pv * w; acc[h * 6 + 5] += w;
    }
  }

  // reduce over es low bits (lane bits 4,5)
#pragma unroll
  for (int k = 0; k < 52; ++k) {
    acc[k] += __shfl_xor(acc[k], 16);
    acc[k] += __shfl_xor(acc[k], 32);
  }
  if ((t & 48) == 0) {
    const int w = t >> 6;          // 0..3
    float* p = &s_part[w][jl][0];
#pragma unroll
    for (int k = 0; k < 52; ++k) p[k] = acc[k];
  }
  __syncthreads();

  if (t < 16) {
    const size_t base = (((size_t)(jt * 32 + b)) * 2 + eq) * 832;
#pragma unroll
    for (int k = 0; k < 52; ++k) {
      float s = s_part[0][t][k] + s_part[1][t][k] + s_part[2][t][k] + s_part[3][t][k];
      pws[base + k * 16 + t] = s;  // lanes 0..15 -> 64B coalesced per k
    }
  }
}

// ---------------------------------------------------------------- k_fin
// grid (16 jt, 32 b), 64 threads (1 wave). Sums the 2 eq-partials, then
// lanes t<16 run the verified softmax epilogue and store a[b][j][4].
__global__ void k_fin(const float* __restrict__ pws, const float* __restrict__ ubk,
                      const float* __restrict__ vbk, float* __restrict__ a) {
  const int t = threadIdx.x;     // 64
  const int jt = blockIdx.x;     // 16
  const int b  = blockIdx.y;     // 32
  __shared__ float s_tot[52][16];
  const int jl = t & 15;
  const int kq = t >> 4;         // 0..3
  const size_t base = ((size_t)(jt * 32 + b)) * 1664;  // 2 records of 832
#pragma unroll
  for (int i = 0; i < 13; ++i) {
    const int k = kq + 4 * i;    // covers 0..51
    s_tot[k][jl] = pws[base + k * 16 + jl] + pws[base + 832 + k * 16 + jl];
  }
  __syncthreads();

  if (t < 16) {
    float tot[52];
#pragma unroll
    for (int k = 0; k < 52; ++k) tot[k] = s_tot[k][t];
    const int jj = jt * 16 + t;
    const float m0 = tot[48] * (1.f / 256.f), m1 = tot[49] * (1.f / 256.f);
    const float m2 = tot[50] * (1.f / 256.f), m3 = tot[51] * (1.f / 256.f);
    const float inv = 0.17677669529663687f;  // 1/sqrt(32)
    float am0 = 0.f, am1 = 0.f, am2 = 0.f, am3 = 0.f;
#pragma unroll
    for (int h = 0; h < 8; ++h) {
      const float qb = ubk[jj * 8 + h] + vbk[b * 8 + h];
      const float c = tot[h * 6 + 4] + qb;
      const float s0 = (tot[h * 6 + 0] - m0 * tot[h * 6 + 5] + c) * inv;
      const float s1 = (tot[h * 6 + 1] - m1 * tot[h * 6 + 5] + c) * inv;
      const float s2 = (tot[h * 6 + 2] - m2 * tot[h * 6 + 5] + c) * inv;
      const float s3 = (tot[h * 6 + 3] - m3 * tot[h * 6 + 5] + c) * inv;
      const float mx = fmaxf(fmaxf(s0, s1), fmaxf(s2, s3));
      const float e0 = expf(s0 - mx), e1 = expf(s1 - mx);
      const float e2 = expf(s2 - mx), e3 = expf(s3 - mx);
      const float r = 1.f / (e0 + e1 + e2 + e3);
      am0 += e0 * r; am1 += e1 * r; am2 += e2 * r; am3 += e3 * r;
    }
    float4 o = make_float4(am0 * 0.125f, am1 * 0.125f, am2 * 0.125f, am3 * 0.125f);
    *(float4*)(a + ((size_t)(b * 256 + jj) << 2)) = o;
  }
}

// ---------------------------------------------------------------- k_ns
__global__ void k_ns(const float* __restrict__ state, const float* __restrict__ o0,
                     const float* __restrict__ o1, const float* __restrict__ o2,
                     const float* __restrict__ a, float* __restrict__ out0) {
  const int t = threadIdx.x;   // 128
  const int e = blockIdx.x;    // 256
  const int b = blockIdx.y;    // 32
  const size_t rowS = ((size_t)b * 256 + e) * 512;
  const size_t rowO = ((size_t)b * 256 + e) * 256;
  if (t < 64) {
    const float4 vv = *(const float4*)(state + rowS + t * 4);
    *(float4*)(out0 + rowS + t * 4) = vv;
  } else {
    const int q0 = t * 4;
    const int j0 = q0 - 256;
    const float4 s  = *(const float4*)(state + rowS + q0);
    const float4 x0 = *(const float4*)(o0 + rowO + j0);
    const float4 x1 = *(const float4*)(o1 + rowO + j0);
    const float4 x2 = *(const float4*)(o2 + rowO + j0);
    const float rs[4] = {s.x, s.y, s.z, s.w};
    const float r0[4] = {x0.x, x0.y, x0.z, x0.w};
    const float r1[4] = {x1.x, x1.y, x1.z, x1.w};
    const float r2[4] = {x2.x, x2.y, x2.z, x2.w};
    float ro[4];
#pragma unroll
    for (int k = 0; k < 4; ++k) {
      const float4 aa = *(const float4*)(a + (((size_t)b * 256) + (j0 + k)) * 4);
      ro[k] = aa.x * rs[k] + aa.y * r0[k] + aa.z * r1[k] + aa.w * r2[k];
    }
    const float4 o = make_float4(ro[0], ro[1], ro[2], ro[3]);
    *(float4*)(out0 + rowS + q0) = o;
  }
}

// ---------------------------------------------------------------- k_at
__global__ void k_at(const float* __restrict__ a, float* __restrict__ out1) {
  const int t = threadIdx.x;   // 320 (1280/4)
  const int q = blockIdx.x;    // 512
  const int b = blockIdx.y;    // 32
  const int l0 = t * 4;
  float v0 = 0.f, v1 = 0.f, v2 = 0.f, v3 = 0.f;
  if (q < 256) {
    if (q == l0) v0 = 1.f; else if (q == l0 + 1) v1 = 1.f;
    else if (q == l0 + 2) v2 = 1.f; else if (q == l0 + 3) v3 = 1.f;
  } else {
    const int j = q - 256;
    const int s = j & 3;
    const float* ap = a + (((size_t)b * 256) + j) * 4;
    float av = 0.f; bool hit = false;
    if (l0 == (q & ~3))              { av = ap[0]; hit = true; }
    else if (l0 == ((512 + j) & ~3)) { av = ap[1]; hit = true; }
    else if (l0 == ((768 + j) & ~3)) { av = ap[2]; hit = true; }
    else if (l0 == ((1024 + j) & ~3)){ av = ap[3]; hit = true; }
    if (hit) { if (s == 0) v0 = av; else if (s == 1) v1 = av; else if (s == 2) v2 = av; else v3 = av; }
  }
  const float4 o = make_float4(v0, v1, v2, v3);
  *(float4*)(out1 + ((size_t)b * 512 + q) * 1280 + l0) = o;
}

extern "C" void kernel_launch(void* const* d_in, const int* in_sizes, int n_in,
                              void* d_out, int out_size, void* d_ws, size_t ws_size,
                              hipStream_t stream) {
  const float* state = (const float*)d_in[0];
  const float* obs0  = (const float*)d_in[1];
  const float* obs1  = (const float*)d_in[2];
  const float* obs2  = (const float*)d_in[3];
  const float* Q     = (const float*)d_in[4];
  const float* Wq    = (const float*)d_in[5];
  const float* bq    = (const float*)d_in[6];
  const float* Wk    = (const float*)d_in[7];
  const float* bk    = (const float*)d_in[8];

  float* out0 = (float*)d_out;                       // new_state [32,256,512]
  float* out1 = out0 + (size_t)32 * 256 * 512;       // atten [32,512,1280]

  float* ws  = (float*)d_ws;
  float* pe  = ws;              // 8192
  float* u   = pe + 8192;       // 65536
  float* v   = u + 65536;       // 8192
  float* wu2 = v + 8192;        // 524288
  float* wv  = wu2 + 524288;    // 65536
  float* ubk = wv + 65536;      // 2048
  float* vbk = ubk + 2048;      // 256
  float* a   = vbk + 256;       // 32768
  float* pws = a + 32768;       // 851968 (16*32*2*832)

  k_uv<<<288, 256, 0, stream>>>(Q, Wq, bq, bk, pe, u, v, ubk, vbk);
  k_w<<<dim3(256, 2), 256, 0, stream>>>(Wk, u, v, wu2, wv);
  k_part<<<dim3(16, 2, 32), 256, 0, stream>>>(state, obs0, obs1, obs2, pe, wu2, wv, pws);
  k_fin<<<dim3(16, 32), 64, 0, stream>>>(pws, ubk, vbk, a);
  k_ns<<<dim3(256, 32), 128, 0, stream>>>(state, obs0, obs1, obs2, a, out0);
  k_at<<<dim3(512, 32), 320, 0, stream>>>(a, out1);
}

// Round 5
// 75.718 us; speedup vs baseline: 1.4301x; 1.4301x over previous
//
#include <hip/hip_runtime.h>
#include <math.h>

// Problem constants: bs=32, en=256, dx=512, dz=256, heads=8, dh=32, L=1280.
//
// Mask is block-diagonal eyes: q<256 -> one-hot row; q=256+j -> exactly 4
// nonzeros {q, 512+j, 768+j, 1024+j} = col 256+j of centered state and col j
// of each centered obs. Wk folded into the query side:
//   score[b,j,h,m] = ( sum_e kb_m[e]*(wu[j,h,e]+wv[b,h,e]) + ubk+vbk ) / sqrt(32)
// with kb_m = raw_m - mean_m + pe, via raw/pe/ones dot rows.
//
// ws layout (floats):
//   pe   [32][256]             @ 0
//   u    [256][256]            @ 8192      (Q[256:]@Wq)
//   v    [32][256]             @ 73728     (pe@Wq + bq)
//   wu2  [8][256e][256j]       @ 81920
//   wv   [32][8][256e]         @ 606208
//   ubk  [256][8]              @ 671744
//   vbk  [32][8]               @ 673792
//   a    [32][256][4]          @ 674048    (head-averaged softmax weights)
//   pws  [16jt][32b][2eq][52k][16jl] @ 706816   (851968 floats, partials)

// ---------------------------------------------------------------- k_uv
__global__ void k_uv(const float* __restrict__ Q, const float* __restrict__ Wq,
                     const float* __restrict__ bq, const float* __restrict__ bk,
                     float* __restrict__ pe, float* __restrict__ u,
                     float* __restrict__ v, float* __restrict__ ubk,
                     float* __restrict__ vbk) {
  __shared__ float row[256];
  const int f = threadIdx.x;
  const int blk = blockIdx.x;
  float rv;
  if (blk < 256) {
    rv = Q[(256 + blk) * 256 + f];
  } else {
    const int b = blk - 256;
    // sinusoidal PE over the BATCH axis (faithful quirk): pos=b, d_model=256
    const float dv = expf(-9.210340371976184f * (float)((f >> 1) << 1) * (1.0f / 256.0f));
    const float ang = (float)b * dv;
    rv = (f & 1) ? cosf(ang) : sinf(ang);
    pe[b * 256 + f] = rv;
  }
  row[f] = rv;
  __syncthreads();
  float acc = (blk < 256) ? 0.0f : bq[f];
  for (int e = 0; e < 256; ++e) acc += row[e] * Wq[e * 256 + f];
  if (blk < 256) u[blk * 256 + f] = acc;
  else           v[(blk - 256) * 256 + f] = acc;
  float val = acc * bk[f];
  val += __shfl_xor(val, 1);  val += __shfl_xor(val, 2);
  val += __shfl_xor(val, 4);  val += __shfl_xor(val, 8);
  val += __shfl_xor(val, 16);
  if ((f & 31) == 0) {
    const int h = f >> 5;
    if (blk < 256) ubk[blk * 8 + h] = val;
    else           vbk[(blk - 256) * 8 + h] = val;
  }
}

// ---------------------------------------------------------------- k_w
__global__ void k_w(const float* __restrict__ Wk, const float* __restrict__ u,
                    const float* __restrict__ v, float* __restrict__ wu2,
                    float* __restrict__ wv) {
  __shared__ float wrow[256];
  const int e = blockIdx.x;
  const int t = threadIdx.x;
  wrow[t] = Wk[e * 256 + t];
  __syncthreads();
  if (blockIdx.y == 0) {
    const float* ur = u + t * 256;
#pragma unroll
    for (int h = 0; h < 8; ++h) {
      float acc = 0.0f;
#pragma unroll
      for (int d = 0; d < 32; ++d) acc += ur[h * 32 + d] * wrow[h * 32 + d];
      wu2[(h * 256 + e) * 256 + t] = acc;
    }
  } else if (t < 32) {
    const float* vr = v + t * 256;
#pragma unroll
    for (int h = 0; h < 8; ++h) {
      float acc = 0.0f;
#pragma unroll
      for (int d = 0; d < 32; ++d) acc += vr[h * 32 + d] * wrow[h * 32 + d];
      wv[(t * 8 + h) * 256 + e] = acc;
    }
  }
}

// ---------------------------------------------------------------- k_part
// grid (16 jt, 2 eq, 32 b), 256 threads = 4 waves. t = jl(0..15)+16*es(0..15).
// Lane owns j = jt*16+jl, e in [eq*128 + es*8, +8). All global loads are
// 64B-per-16-lane coalesced. NO min-waves clamp: 52 accumulators must stay
// in VGPRs (round 4's __launch_bounds__(256,5) forced 48 VGPRs -> scratch
// spill -> 100 MB of spill writes). Reduce: shfl over lane bits 4,5 then LDS
// across the 4 waves; lanes t<16 write a [52][16] partial record to pws.
__global__ __launch_bounds__(256)
void k_part(const float* __restrict__ state, const float* __restrict__ o0,
            const float* __restrict__ o1, const float* __restrict__ o2,
            const float* __restrict__ pe, const float* __restrict__ wu2,
            const float* __restrict__ wv, float* __restrict__ pws) {
  const int t = threadIdx.x;
  const int jl = t & 15;
  const int es = t >> 4;           // 0..15
  const int jt = blockIdx.x;       // 0..15
  const int eq = blockIdx.y;       // 0..1
  const int b  = blockIdx.z;       // 0..31
  const int j = jt * 16 + jl;

  __shared__ float s_wv[1024];     // [h][128]  (this eq's e-slice)
  __shared__ float s_pe[128];
  __shared__ float s_part[4][16][52];

  for (int i = t; i < 1024; i += 256)
    s_wv[i] = wv[b * 2048 + (i >> 7) * 256 + eq * 128 + (i & 127)];
  if (t < 128) s_pe[t] = pe[b * 256 + eq * 128 + t];
  __syncthreads();

  // acc[h*6+c]: c=0..3 dR(state,o0,o1,o2), c=4 dP(pe), c=5 dO(ones); 48..51 sm
  float acc[52];
#pragma unroll
  for (int k = 0; k < 52; ++k) acc[k] = 0.f;

  const float* ps = state + (size_t)b * 256 * 512 + 256 + j;
  const float* p0 = o0 + (size_t)b * 256 * 256 + j;
  const float* p1 = o1 + (size_t)b * 256 * 256 + j;
  const float* p2 = o2 + (size_t)b * 256 * 256 + j;
  const float* pwu = wu2 + j;      // + (h*256+e)*256

#pragma unroll
  for (int it = 0; it < 8; ++it) {
    const int el = es * 8 + it;    // 0..127 within this eq slice
    const int e = eq * 128 + el;   // global e
    const float s  = ps[(size_t)e * 512];
    const float x0 = p0[(size_t)e * 256];
    const float x1 = p1[(size_t)e * 256];
    const float x2 = p2[(size_t)e * 256];
    const float pv = s_pe[el];
    acc[48] += s; acc[49] += x0; acc[50] += x1; acc[51] += x2;
#pragma unroll
    for (int h = 0; h < 8; ++h) {
      const float w = pwu[(size_t)(h * 256 + e) * 256] + s_wv[h * 128 + el];
      acc[h * 6 + 0] += s * w;  acc[h * 6 + 1] += x0 * w;
      acc[h * 6 + 2] += x1 * w; acc[h * 6 + 3] += x2 * w;
      acc[h * 6 + 4] += pv * w; acc[h * 6 + 5] += w;
    }
  }

  // reduce over es low bits (lane bits 4,5)
#pragma unroll
  for (int k = 0; k < 52; ++k) {
    acc[k] += __shfl_xor(acc[k], 16);
    acc[k] += __shfl_xor(acc[k], 32);
  }
  if ((t & 48) == 0) {
    const int w = t >> 6;          // 0..3
    float* p = &s_part[w][jl][0];
#pragma unroll
    for (int k = 0; k < 52; ++k) p[k] = acc[k];
  }
  __syncthreads();

  if (t < 16) {
    const size_t base = (((size_t)(jt * 32 + b)) * 2 + eq) * 832;
#pragma unroll
    for (int k = 0; k < 52; ++k) {
      float s = s_part[0][t][k] + s_part[1][t][k] + s_part[2][t][k] + s_part[3][t][k];
      pws[base + k * 16 + t] = s;  // lanes 0..15 -> 64B coalesced per k
    }
  }
}

// ---------------------------------------------------------------- k_fin
// grid (16 jt, 32 b), 64 threads (1 wave). Sums the 2 eq-partials, then
// lanes t<16 run the verified softmax epilogue and store a[b][j][4].
__global__ void k_fin(const float* __restrict__ pws, const float* __restrict__ ubk,
                      const float* __restrict__ vbk, float* __restrict__ a) {
  const int t = threadIdx.x;     // 64
  const int jt = blockIdx.x;     // 16
  const int b  = blockIdx.y;     // 32
  __shared__ float s_tot[52][16];
  const int jl = t & 15;
  const int kq = t >> 4;         // 0..3
  const size_t base = ((size_t)(jt * 32 + b)) * 1664;  // 2 records of 832
#pragma unroll
  for (int i = 0; i < 13; ++i) {
    const int k = kq + 4 * i;    // covers 0..51
    s_tot[k][jl] = pws[base + k * 16 + jl] + pws[base + 832 + k * 16 + jl];
  }
  __syncthreads();

  if (t < 16) {
    float tot[52];
#pragma unroll
    for (int k = 0; k < 52; ++k) tot[k] = s_tot[k][t];
    const int jj = jt * 16 + t;
    const float m0 = tot[48] * (1.f / 256.f), m1 = tot[49] * (1.f / 256.f);
    const float m2 = tot[50] * (1.f / 256.f), m3 = tot[51] * (1.f / 256.f);
    const float inv = 0.17677669529663687f;  // 1/sqrt(32)
    float am0 = 0.f, am1 = 0.f, am2 = 0.f, am3 = 0.f;
#pragma unroll
    for (int h = 0; h < 8; ++h) {
      const float qb = ubk[jj * 8 + h] + vbk[b * 8 + h];
      const float c = tot[h * 6 + 4] + qb;
      const float s0 = (tot[h * 6 + 0] - m0 * tot[h * 6 + 5] + c) * inv;
      const float s1 = (tot[h * 6 + 1] - m1 * tot[h * 6 + 5] + c) * inv;
      const float s2 = (tot[h * 6 + 2] - m2 * tot[h * 6 + 5] + c) * inv;
      const float s3 = (tot[h * 6 + 3] - m3 * tot[h * 6 + 5] + c) * inv;
      const float mx = fmaxf(fmaxf(s0, s1), fmaxf(s2, s3));
      const float e0 = expf(s0 - mx), e1 = expf(s1 - mx);
      const float e2 = expf(s2 - mx), e3 = expf(s3 - mx);
      const float r = 1.f / (e0 + e1 + e2 + e3);
      am0 += e0 * r; am1 += e1 * r; am2 += e2 * r; am3 += e3 * r;
    }
    float4 o = make_float4(am0 * 0.125f, am1 * 0.125f, am2 * 0.125f, am3 * 0.125f);
    *(float4*)(a + ((size_t)(b * 256 + jj) << 2)) = o;
  }
}

// ---------------------------------------------------------------- k_ns
__global__ void k_ns(const float* __restrict__ state, const float* __restrict__ o0,
                     const float* __restrict__ o1, const float* __restrict__ o2,
                     const float* __restrict__ a, float* __restrict__ out0) {
  const int t = threadIdx.x;   // 128
  const int e = blockIdx.x;    // 256
  const int b = blockIdx.y;    // 32
  const size_t rowS = ((size_t)b * 256 + e) * 512;
  const size_t rowO = ((size_t)b * 256 + e) * 256;
  if (t < 64) {
    const float4 vv = *(const float4*)(state + rowS + t * 4);
    *(float4*)(out0 + rowS + t * 4) = vv;
  } else {
    const int q0 = t * 4;
    const int j0 = q0 - 256;
    const float4 s  = *(const float4*)(state + rowS + q0);
    const float4 x0 = *(const float4*)(o0 + rowO + j0);
    const float4 x1 = *(const float4*)(o1 + rowO + j0);
    const float4 x2 = *(const float4*)(o2 + rowO + j0);
    const float rs[4] = {s.x, s.y, s.z, s.w};
    const float r0[4] = {x0.x, x0.y, x0.z, x0.w};
    const float r1[4] = {x1.x, x1.y, x1.z, x1.w};
    const float r2[4] = {x2.x, x2.y, x2.z, x2.w};
    float ro[4];
#pragma unroll
    for (int k = 0; k < 4; ++k) {
      const float4 aa = *(const float4*)(a + (((size_t)b * 256) + (j0 + k)) * 4);
      ro[k] = aa.x * rs[k] + aa.y * r0[k] + aa.z * r1[k] + aa.w * r2[k];
    }
    const float4 o = make_float4(ro[0], ro[1], ro[2], ro[3]);
    *(float4*)(out0 + rowS + q0) = o;
  }
}

// ---------------------------------------------------------------- k_at
__global__ void k_at(const float* __restrict__ a, float* __restrict__ out1) {
  const int t = threadIdx.x;   // 320 (1280/4)
  const int q = blockIdx.x;    // 512
  const int b = blockIdx.y;    // 32
  const int l0 = t * 4;
  float v0 = 0.f, v1 = 0.f, v2 = 0.f, v3 = 0.f;
  if (q < 256) {
    if (q == l0) v0 = 1.f; else if (q == l0 + 1) v1 = 1.f;
    else if (q == l0 + 2) v2 = 1.f; else if (q == l0 + 3) v3 = 1.f;
  } else {
    const int j = q - 256;
    const int s = j & 3;
    const float* ap = a + (((size_t)b * 256) + j) * 4;
    float av = 0.f; bool hit = false;
    if (l0 == (q & ~3))              { av = ap[0]; hit = true; }
    else if (l0 == ((512 + j) & ~3)) { av = ap[1]; hit = true; }
    else if (l0 == ((768 + j) & ~3)) { av = ap[2]; hit = true; }
    else if (l0 == ((1024 + j) & ~3)){ av = ap[3]; hit = true; }
    if (hit) { if (s == 0) v0 = av; else if (s == 1) v1 = av; else if (s == 2) v2 = av; else v3 = av; }
  }
  const float4 o = make_float4(v0, v1, v2, v3);
  *(float4*)(out1 + ((size_t)b * 512 + q) * 1280 + l0) = o;
}

extern "C" void kernel_launch(void* const* d_in, const int* in_sizes, int n_in,
                              void* d_out, int out_size, void* d_ws, size_t ws_size,
                              hipStream_t stream) {
  const float* state = (const float*)d_in[0];
  const float* obs0  = (const float*)d_in[1];
  const float* obs1  = (const float*)d_in[2];
  const float* obs2  = (const float*)d_in[3];
  const float* Q     = (const float*)d_in[4];
  const float* Wq    = (const float*)d_in[5];
  const float* bq    = (const float*)d_in[6];
  const float* Wk    = (const float*)d_in[7];
  const float* bk    = (const float*)d_in[8];

  float* out0 = (float*)d_out;                       // new_state [32,256,512]
  float* out1 = out0 + (size_t)32 * 256 * 512;       // atten [32,512,1280]

  float* ws  = (float*)d_ws;
  float* pe  = ws;              // 8192
  float* u   = pe + 8192;       // 65536
  float* v   = u + 65536;       // 8192
  float* wu2 = v + 8192;        // 524288
  float* wv  = wu2 + 524288;    // 65536
  float* ubk = wv + 65536;      // 2048
  float* vbk = ubk + 2048;      // 256
  float* a   = vbk + 256;       // 32768
  float* pws = a + 32768;       // 851968 (16*32*2*832)

  k_uv<<<288, 256, 0, stream>>>(Q, Wq, bq, bk, pe, u, v, ubk, vbk);
  k_w<<<dim3(256, 2), 256, 0, stream>>>(Wk, u, v, wu2, wv);
  k_part<<<dim3(16, 2, 32), 256, 0, stream>>>(state, obs0, obs1, obs2, pe, wu2, wv, pws);
  k_fin<<<dim3(16, 32), 64, 0, stream>>>(pws, ubk, vbk, a);
  k_ns<<<dim3(256, 32), 128, 0, stream>>>(state, obs0, obs1, obs2, a, out0);
  k_at<<<dim3(512, 32), 320, 0, stream>>>(a, out1);
}

// Round 6
// 75.241 us; speedup vs baseline: 1.4392x; 1.0063x over previous
//
#include <hip/hip_runtime.h>
#include <math.h>

// Problem constants: bs=32, en=256, dx=512, dz=256, heads=8, dh=32, L=1280.
//
// Mask is block-diagonal eyes: q<256 -> one-hot row; q=256+j -> exactly 4
// nonzeros {q, 512+j, 768+j, 1024+j} = col 256+j of centered state and col j
// of each centered obs. Wk folded into the query side:
//   score[b,j,h,m] = ( dR_m - mean_m*dO + dP + qb ) / sqrt(32)
// where dP (pe.w dot) and qb (qh.bk) are IDENTICAL across the 4 softmax
// candidates m -> softmax shift-invariance cancels them. Only
//   dR_m[j,h] = sum_e raw_m[b,e,j]*w[b,j,h,e],  dO[j,h] = sum_e w
// are needed, with w = wu[j,h,e] + wv[b,h,e].
//
// ws layout (floats):
//   u    [256][256]            @ 0         (Q[256:]@Wq)
//   v    [32][256]             @ 65536     (pe@Wq + bq; pe lives only in k_uv LDS)
//   wu2  [8][256e][256j]       @ 73728
//   wv   [32][8][256e]         @ 598016
//   a    [32][256][4]          @ 663552    (head-averaged softmax weights)
//   pws  [16jt][32b][2eq][44k][16jl] @ 696320   (720896 floats, partials)
// total 1,417,216 floats = 5.67 MB

// ---------------------------------------------------------------- k_uv
// blocks 0..255  : j-block -> u[j][f]
// blocks 256..287: b-block -> v[b][f]  (pe row built in LDS, never stored)
__global__ void k_uv(const float* __restrict__ Q, const float* __restrict__ Wq,
                     const float* __restrict__ bq,
                     float* __restrict__ u, float* __restrict__ v) {
  __shared__ float row[256];
  const int f = threadIdx.x;
  const int blk = blockIdx.x;
  float rv;
  if (blk < 256) {
    rv = Q[(256 + blk) * 256 + f];
  } else {
    const int b = blk - 256;
    // sinusoidal PE over the BATCH axis (faithful quirk): pos=b, d_model=256
    const float dv = expf(-9.210340371976184f * (float)((f >> 1) << 1) * (1.0f / 256.0f));
    const float ang = (float)b * dv;
    rv = (f & 1) ? cosf(ang) : sinf(ang);
  }
  row[f] = rv;
  __syncthreads();
  float acc = (blk < 256) ? 0.0f : bq[f];
  for (int e = 0; e < 256; ++e) acc += row[e] * Wq[e * 256 + f];
  if (blk < 256) u[blk * 256 + f] = acc;
  else           v[(blk - 256) * 256 + f] = acc;
}

// ---------------------------------------------------------------- k_w
__global__ void k_w(const float* __restrict__ Wk, const float* __restrict__ u,
                    const float* __restrict__ v, float* __restrict__ wu2,
                    float* __restrict__ wv) {
  __shared__ float wrow[256];
  const int e = blockIdx.x;
  const int t = threadIdx.x;
  wrow[t] = Wk[e * 256 + t];
  __syncthreads();
  if (blockIdx.y == 0) {
    const float* ur = u + t * 256;
#pragma unroll
    for (int h = 0; h < 8; ++h) {
      float acc = 0.0f;
#pragma unroll
      for (int d = 0; d < 32; ++d) acc += ur[h * 32 + d] * wrow[h * 32 + d];
      wu2[(h * 256 + e) * 256 + t] = acc;
    }
  } else if (t < 32) {
    const float* vr = v + t * 256;
#pragma unroll
    for (int h = 0; h < 8; ++h) {
      float acc = 0.0f;
#pragma unroll
      for (int d = 0; d < 32; ++d) acc += vr[h * 32 + d] * wrow[h * 32 + d];
      wv[(t * 8 + h) * 256 + e] = acc;
    }
  }
}

// ---------------------------------------------------------------- k_part
// grid (16 jt, 2 eq, 32 b), 512 threads = 8 waves.
// t = jl(0..15) + 16*es(0..15) + 256*hp(0..1). Lane owns j = jt*16+jl,
// e in [eq*128 + es*8, +8), heads h = hp*4 .. hp*4+3.
// 24 accumulators/thread (low VGPR -> high occupancy), 64 loads/thread,
// all 64B-per-16-lane coalesced. Reduce: shfl over lane bits 4,5 -> LDS
// across 8 waves -> [44][16] partial record to pws.
__global__ __launch_bounds__(512)
void k_part(const float* __restrict__ state, const float* __restrict__ o0,
            const float* __restrict__ o1, const float* __restrict__ o2,
            const float* __restrict__ wu2, const float* __restrict__ wv,
            float* __restrict__ pws) {
  const int t = threadIdx.x;
  const int jl = t & 15;
  const int es = (t >> 4) & 15;    // 0..15
  const int hp = t >> 8;           // 0..1
  const int jt = blockIdx.x;       // 0..15
  const int eq = blockIdx.y;       // 0..1
  const int b  = blockIdx.z;       // 0..31
  const int j = jt * 16 + jl;

  __shared__ float s_wv[1024];     // [h][128]  (this eq's e-slice)
  __shared__ float s_part[8][16][25];

  for (int i = t; i < 1024; i += 512)
    s_wv[i] = wv[b * 2048 + (i >> 7) * 256 + eq * 128 + (i & 127)];
  __syncthreads();

  // acc[hh*5+c]: c=0..3 dR(state,o0,o1,o2), c=4 dO(ones); 20..23 raw sums
  float acc[24];
#pragma unroll
  for (int k = 0; k < 24; ++k) acc[k] = 0.f;

  const float* ps = state + (size_t)b * 256 * 512 + 256 + j;
  const float* p0 = o0 + (size_t)b * 256 * 256 + j;
  const float* p1 = o1 + (size_t)b * 256 * 256 + j;
  const float* p2 = o2 + (size_t)b * 256 * 256 + j;
  const float* pwu = wu2 + (size_t)hp * 4 * 256 * 256 + j;  // + (hh*256+e)*256
  const float* pwv = s_wv + hp * 4 * 128;                   // + hh*128+el

#pragma unroll
  for (int it = 0; it < 8; ++it) {
    const int el = es * 8 + it;    // 0..127 within this eq slice
    const int e = eq * 128 + el;   // global e
    const float s  = ps[(size_t)e * 512];
    const float x0 = p0[(size_t)e * 256];
    const float x1 = p1[(size_t)e * 256];
    const float x2 = p2[(size_t)e * 256];
    acc[20] += s; acc[21] += x0; acc[22] += x1; acc[23] += x2;
#pragma unroll
    for (int hh = 0; hh < 4; ++hh) {
      const float w = pwu[(size_t)(hh * 256 + e) * 256] + pwv[hh * 128 + el];
      acc[hh * 5 + 0] += s * w;  acc[hh * 5 + 1] += x0 * w;
      acc[hh * 5 + 2] += x1 * w; acc[hh * 5 + 3] += x2 * w;
      acc[hh * 5 + 4] += w;
    }
  }

  // reduce over es low bits (lane bits 4,5)
#pragma unroll
  for (int k = 0; k < 24; ++k) {
    acc[k] += __shfl_xor(acc[k], 16);
    acc[k] += __shfl_xor(acc[k], 32);
  }
  if ((t & 48) == 0) {
    const int w = t >> 6;          // 0..7
    float* p = &s_part[w][jl][0];
#pragma unroll
    for (int k = 0; k < 24; ++k) p[k] = acc[k];
  }
  __syncthreads();

  // record layout: k = h*5+c for h<8 (0..39), raw sums at 40..43
  const size_t base = (((size_t)(jt * 32 + b)) * 2 + eq) * 704;
  if (t < 16) {
    // h = 0..3 from waves 0..3, plus the raw sums
#pragma unroll
    for (int k = 0; k < 20; ++k) {
      float s = s_part[0][t][k] + s_part[1][t][k] + s_part[2][t][k] + s_part[3][t][k];
      pws[base + k * 16 + t] = s;
    }
#pragma unroll
    for (int c = 0; c < 4; ++c) {
      float s = s_part[0][t][20 + c] + s_part[1][t][20 + c] +
                s_part[2][t][20 + c] + s_part[3][t][20 + c];
      pws[base + (40 + c) * 16 + t] = s;
    }
  } else if (t >= 256 && t < 272) {
    const int l = t & 15;
    // h = 4..7 from waves 4..7
#pragma unroll
    for (int k = 0; k < 20; ++k) {
      float s = s_part[4][l][k] + s_part[5][l][k] + s_part[6][l][k] + s_part[7][l][k];
      pws[base + (20 + k) * 16 + l] = s;
    }
  }
}

// ---------------------------------------------------------------- k_fin
// grid (16 jt, 32 b), 64 threads (1 wave). Sums the 2 eq-partials, then
// lanes t<16 run the softmax epilogue (shift-invariant form) and store a.
__global__ void k_fin(const float* __restrict__ pws, float* __restrict__ a) {
  const int t = threadIdx.x;     // 64
  const int jt = blockIdx.x;     // 16
  const int b  = blockIdx.y;     // 32
  __shared__ float s_tot[44][16];
  const int jl = t & 15;
  const int kq = t >> 4;         // 0..3
  const size_t base = ((size_t)(jt * 32 + b)) * 1408;  // 2 records of 704
#pragma unroll
  for (int i = 0; i < 11; ++i) {
    const int k = kq + 4 * i;    // covers 0..43
    s_tot[k][jl] = pws[base + k * 16 + jl] + pws[base + 704 + k * 16 + jl];
  }
  __syncthreads();

  if (t < 16) {
    float tot[44];
#pragma unroll
    for (int k = 0; k < 44; ++k) tot[k] = s_tot[k][t];
    const float m0 = tot[40] * (1.f / 256.f), m1 = tot[41] * (1.f / 256.f);
    const float m2 = tot[42] * (1.f / 256.f), m3 = tot[43] * (1.f / 256.f);
    const float inv = 0.17677669529663687f;  // 1/sqrt(32)
    float am0 = 0.f, am1 = 0.f, am2 = 0.f, am3 = 0.f;
#pragma unroll
    for (int h = 0; h < 8; ++h) {
      const float dO = tot[h * 5 + 4];
      const float s0 = (tot[h * 5 + 0] - m0 * dO) * inv;
      const float s1 = (tot[h * 5 + 1] - m1 * dO) * inv;
      const float s2 = (tot[h * 5 + 2] - m2 * dO) * inv;
      const float s3 = (tot[h * 5 + 3] - m3 * dO) * inv;
      const float mx = fmaxf(fmaxf(s0, s1), fmaxf(s2, s3));
      const float e0 = expf(s0 - mx), e1 = expf(s1 - mx);
      const float e2 = expf(s2 - mx), e3 = expf(s3 - mx);
      const float r = 1.f / (e0 + e1 + e2 + e3);
      am0 += e0 * r; am1 += e1 * r; am2 += e2 * r; am3 += e3 * r;
    }
    const int jj = jt * 16 + t;
    float4 o = make_float4(am0 * 0.125f, am1 * 0.125f, am2 * 0.125f, am3 * 0.125f);
    *(float4*)(a + ((size_t)(b * 256 + jj) << 2)) = o;
  }
}

// ---------------------------------------------------------------- k_ns
__global__ void k_ns(const float* __restrict__ state, const float* __restrict__ o0,
                     const float* __restrict__ o1, const float* __restrict__ o2,
                     const float* __restrict__ a, float* __restrict__ out0) {
  const int t = threadIdx.x;   // 128
  const int e = blockIdx.x;    // 256
  const int b = blockIdx.y;    // 32
  const size_t rowS = ((size_t)b * 256 + e) * 512;
  const size_t rowO = ((size_t)b * 256 + e) * 256;
  if (t < 64) {
    const float4 vv = *(const float4*)(state + rowS + t * 4);
    *(float4*)(out0 + rowS + t * 4) = vv;
  } else {
    const int q0 = t * 4;
    const int j0 = q0 - 256;
    const float4 s  = *(const float4*)(state + rowS + q0);
    const float4 x0 = *(const float4*)(o0 + rowO + j0);
    const float4 x1 = *(const float4*)(o1 + rowO + j0);
    const float4 x2 = *(const float4*)(o2 + rowO + j0);
    const float rs[4] = {s.x, s.y, s.z, s.w};
    const float r0[4] = {x0.x, x0.y, x0.z, x0.w};
    const float r1[4] = {x1.x, x1.y, x1.z, x1.w};
    const float r2[4] = {x2.x, x2.y, x2.z, x2.w};
    float ro[4];
#pragma unroll
    for (int k = 0; k < 4; ++k) {
      const float4 aa = *(const float4*)(a + (((size_t)b * 256) + (j0 + k)) * 4);
      ro[k] = aa.x * rs[k] + aa.y * r0[k] + aa.z * r1[k] + aa.w * r2[k];
    }
    const float4 o = make_float4(ro[0], ro[1], ro[2], ro[3]);
    *(float4*)(out0 + rowS + q0) = o;
  }
}

// ---------------------------------------------------------------- k_at
__global__ void k_at(const float* __restrict__ a, float* __restrict__ out1) {
  const int t = threadIdx.x;   // 320 (1280/4)
  const int q = blockIdx.x;    // 512
  const int b = blockIdx.y;    // 32
  const int l0 = t * 4;
  float v0 = 0.f, v1 = 0.f, v2 = 0.f, v3 = 0.f;
  if (q < 256) {
    if (q == l0) v0 = 1.f; else if (q == l0 + 1) v1 = 1.f;
    else if (q == l0 + 2) v2 = 1.f; else if (q == l0 + 3) v3 = 1.f;
  } else {
    const int j = q - 256;
    const int s = j & 3;
    const float* ap = a + (((size_t)b * 256) + j) * 4;
    float av = 0.f; bool hit = false;
    if (l0 == (q & ~3))              { av = ap[0]; hit = true; }
    else if (l0 == ((512 + j) & ~3)) { av = ap[1]; hit = true; }
    else if (l0 == ((768 + j) & ~3)) { av = ap[2]; hit = true; }
    else if (l0 == ((1024 + j) & ~3)){ av = ap[3]; hit = true; }
    if (hit) { if (s == 0) v0 = av; else if (s == 1) v1 = av; else if (s == 2) v2 = av; else v3 = av; }
  }
  const float4 o = make_float4(v0, v1, v2, v3);
  *(float4*)(out1 + ((size_t)b * 512 + q) * 1280 + l0) = o;
}

extern "C" void kernel_launch(void* const* d_in, const int* in_sizes, int n_in,
                              void* d_out, int out_size, void* d_ws, size_t ws_size,
                              hipStream_t stream) {
  const float* state = (const float*)d_in[0];
  const float* obs0  = (const float*)d_in[1];
  const float* obs1  = (const float*)d_in[2];
  const float* obs2  = (const float*)d_in[3];
  const float* Q     = (const float*)d_in[4];
  const float* Wq    = (const float*)d_in[5];
  const float* bq    = (const float*)d_in[6];
  const float* Wk    = (const float*)d_in[7];
  // d_in[8] = bk: cancels in the 4-way softmax (shift invariance), unused.

  float* out0 = (float*)d_out;                       // new_state [32,256,512]
  float* out1 = out0 + (size_t)32 * 256 * 512;       // atten [32,512,1280]

  float* ws  = (float*)d_ws;
  float* u   = ws;              // 65536
  float* v   = u + 65536;       // 8192
  float* wu2 = v + 8192;        // 524288
  float* wv  = wu2 + 524288;    // 65536
  float* a   = wv + 65536;      // 32768
  float* pws = a + 32768;       // 720896 (16*32*2*704)

  k_uv<<<288, 256, 0, stream>>>(Q, Wq, bq, u, v);
  k_w<<<dim3(256, 2), 256, 0, stream>>>(Wk, u, v, wu2, wv);
  k_part<<<dim3(16, 2, 32), 512, 0, stream>>>(state, obs0, obs1, obs2, wu2, wv, pws);
  k_fin<<<dim3(16, 32), 64, 0, stream>>>(pws, a);
  k_ns<<<dim3(256, 32), 128, 0, stream>>>(state, obs0, obs1, obs2, a, out0);
  k_at<<<dim3(512, 32), 320, 0, stream>>>(a, out1);
}

// Round 7
// 70.498 us; speedup vs baseline: 1.5360x; 1.0673x over previous
//
#include <hip/hip_runtime.h>
#include <math.h>

// Problem constants: bs=32, en=256, dx=512, dz=256, heads=8, dh=32, L=1280.
//
// Mask is block-diagonal eyes: q<256 -> one-hot row; q=256+j -> exactly 4
// nonzeros {q, 512+j, 768+j, 1024+j} = col 256+j of centered state and col j
// of each centered obs. Wk folded into the query side; pe-dot and bk-dot are
// constant across the 4 softmax candidates -> cancel (shift invariance).
// Needed per (b,j,h):  dR_m = sum_e raw_m*w,  dO = sum_e w,
// with w = wu[j,h,e] + wv[b,h,e].
//
// Pipeline (3 launches): k_uv -> k_w -> k_mega.
// k_mega roles by blockIdx.x:
//   A [0,512):    (jt,b): dot + softmax in-block, then writes out0 cols 256+j
//                 (raw slice is L2-hot from phase 1) and out1 rows q=256+j.
//   B [512,1536): out0[b][e][0:256] = state copy (a-independent).
//   C [1536,2560): out1 one-hot rows q<256 (a-independent).
//
// ws layout (floats): u[256][256]@0, v[32][256]@65536, wu2[8][256e][256j]@73728,
// wv[32][8][256e]@598016. Total 663552 floats = 2.65 MB.

// ---------------------------------------------------------------- k_uv
// blocks 0..255  : j-block -> u[j][f] = Q[256+j]@Wq
// blocks 256..287: b-block -> v[b][f] = pe[b]@Wq + bq (pe built in LDS only)
__global__ void k_uv(const float* __restrict__ Q, const float* __restrict__ Wq,
                     const float* __restrict__ bq,
                     float* __restrict__ u, float* __restrict__ v) {
  __shared__ float row[256];
  const int f = threadIdx.x;
  const int blk = blockIdx.x;
  float rv;
  if (blk < 256) {
    rv = Q[(256 + blk) * 256 + f];
  } else {
    const int b = blk - 256;
    // sinusoidal PE over the BATCH axis (faithful quirk): pos=b, d_model=256
    const float dv = expf(-9.210340371976184f * (float)((f >> 1) << 1) * (1.0f / 256.0f));
    const float ang = (float)b * dv;
    rv = (f & 1) ? cosf(ang) : sinf(ang);
  }
  row[f] = rv;
  __syncthreads();
  float acc = (blk < 256) ? 0.0f : bq[f];
  for (int e = 0; e < 256; ++e) acc += row[e] * Wq[e * 256 + f];
  if (blk < 256) u[blk * 256 + f] = acc;
  else           v[(blk - 256) * 256 + f] = acc;
}

// ---------------------------------------------------------------- k_w
__global__ void k_w(const float* __restrict__ Wk, const float* __restrict__ u,
                    const float* __restrict__ v, float* __restrict__ wu2,
                    float* __restrict__ wv) {
  __shared__ float wrow[256];
  const int e = blockIdx.x;
  const int t = threadIdx.x;
  wrow[t] = Wk[e * 256 + t];
  __syncthreads();
  if (blockIdx.y == 0) {
    const float* ur = u + t * 256;
#pragma unroll
    for (int h = 0; h < 8; ++h) {
      float acc = 0.0f;
#pragma unroll
      for (int d = 0; d < 32; ++d) acc += ur[h * 32 + d] * wrow[h * 32 + d];
      wu2[(h * 256 + e) * 256 + t] = acc;
    }
  } else if (t < 32) {
    const float* vr = v + t * 256;
#pragma unroll
    for (int h = 0; h < 8; ++h) {
      float acc = 0.0f;
#pragma unroll
      for (int d = 0; d < 32; ++d) acc += vr[h * 32 + d] * wrow[h * 32 + d];
      wv[(t * 8 + h) * 256 + e] = acc;
    }
  }
}

// ---------------------------------------------------------------- k_mega
__global__ __launch_bounds__(512)
void k_mega(const float* __restrict__ state, const float* __restrict__ o0,
            const float* __restrict__ o1, const float* __restrict__ o2,
            const float* __restrict__ wu2, const float* __restrict__ wv,
            float* __restrict__ out0, float* __restrict__ out1) {
  const int blk = blockIdx.x;
  const int t = threadIdx.x;

  if (blk < 512) {
    // ================= role A: dot + softmax + dependent outputs ========
    const int jt = blk & 15;       // 0..15
    const int b  = blk >> 4;       // 0..31
    __shared__ float s_wv[2048];           // [h][256]
    __shared__ float s_part[8][16][25];    // [wave][jl][24+pad]
    __shared__ float s_a[16][4];           // per-j softmax weights

    for (int i = t; i < 2048; i += 512) s_wv[i] = wv[b * 2048 + i];
    __syncthreads();

    // t = jl(0..15) + 16*es(0..15) + 256*hp(0..1); heads h = hp*4..hp*4+3
    const int jl = t & 15;
    const int es = (t >> 4) & 15;
    const int hp = t >> 8;
    const int j = jt * 16 + jl;

    // acc[hh*5+c]: c=0..3 dR(state,o0,o1,o2), c=4 dO; 20..23 raw sums
    float acc[24];
#pragma unroll
    for (int k = 0; k < 24; ++k) acc[k] = 0.f;

    const float* ps = state + (size_t)b * 256 * 512 + 256 + j;
    const float* p0 = o0 + (size_t)b * 256 * 256 + j;
    const float* p1 = o1 + (size_t)b * 256 * 256 + j;
    const float* p2 = o2 + (size_t)b * 256 * 256 + j;
    const float* pwu = wu2 + (size_t)hp * 4 * 256 * 256 + j;  // + (hh*256+e)*256
    const float* pwv = s_wv + hp * 4 * 256;                   // + hh*256+e

#pragma unroll
    for (int it = 0; it < 16; ++it) {
      const int e = es * 16 + it;
      const float s  = ps[(size_t)e * 512];
      const float x0 = p0[(size_t)e * 256];
      const float x1 = p1[(size_t)e * 256];
      const float x2 = p2[(size_t)e * 256];
      acc[20] += s; acc[21] += x0; acc[22] += x1; acc[23] += x2;
#pragma unroll
      for (int hh = 0; hh < 4; ++hh) {
        const float w = pwu[(size_t)(hh * 256 + e) * 256] + pwv[hh * 256 + e];
        acc[hh * 5 + 0] += s * w;  acc[hh * 5 + 1] += x0 * w;
        acc[hh * 5 + 2] += x1 * w; acc[hh * 5 + 3] += x2 * w;
        acc[hh * 5 + 4] += w;
      }
    }

    // reduce es-low-2-bits (lane bits 4,5), then across waves via LDS
#pragma unroll
    for (int k = 0; k < 24; ++k) {
      acc[k] += __shfl_xor(acc[k], 16);
      acc[k] += __shfl_xor(acc[k], 32);
    }
    if ((t & 48) == 0) {
      const int w = t >> 6;        // 0..7
      float* p = &s_part[w][jl][0];
#pragma unroll
      for (int k = 0; k < 24; ++k) p[k] = acc[k];
    }
    __syncthreads();

    if (t < 16) {
      // tot layout: h<8 at h*5+c (0..39), raw sums at 40..43
      float tot[44];
#pragma unroll
      for (int k = 0; k < 20; ++k)
        tot[k] = s_part[0][t][k] + s_part[1][t][k] + s_part[2][t][k] + s_part[3][t][k];
#pragma unroll
      for (int k = 0; k < 20; ++k)
        tot[20 + k] = s_part[4][t][k] + s_part[5][t][k] + s_part[6][t][k] + s_part[7][t][k];
#pragma unroll
      for (int c = 0; c < 4; ++c)
        tot[40 + c] = s_part[0][t][20 + c] + s_part[1][t][20 + c] +
                      s_part[2][t][20 + c] + s_part[3][t][20 + c];

      const float m0 = tot[40] * (1.f / 256.f), m1 = tot[41] * (1.f / 256.f);
      const float m2 = tot[42] * (1.f / 256.f), m3 = tot[43] * (1.f / 256.f);
      const float inv = 0.17677669529663687f;  // 1/sqrt(32)
      float am0 = 0.f, am1 = 0.f, am2 = 0.f, am3 = 0.f;
#pragma unroll
      for (int h = 0; h < 8; ++h) {
        const float dO = tot[h * 5 + 4];
        const float s0 = (tot[h * 5 + 0] - m0 * dO) * inv;
        const float s1 = (tot[h * 5 + 1] - m1 * dO) * inv;
        const float s2 = (tot[h * 5 + 2] - m2 * dO) * inv;
        const float s3 = (tot[h * 5 + 3] - m3 * dO) * inv;
        const float mx = fmaxf(fmaxf(s0, s1), fmaxf(s2, s3));
        const float e0 = expf(s0 - mx), e1 = expf(s1 - mx);
        const float e2 = expf(s2 - mx), e3 = expf(s3 - mx);
        const float r = 1.f / (e0 + e1 + e2 + e3);
        am0 += e0 * r; am1 += e1 * r; am2 += e2 * r; am3 += e3 * r;
      }
      s_a[t][0] = am0 * 0.125f; s_a[t][1] = am1 * 0.125f;
      s_a[t][2] = am2 * 0.125f; s_a[t][3] = am3 * 0.125f;
    }
    __syncthreads();

    // ---- phase 2: out0[b][e][256+j] (raw slice L2-hot from phase 1)
    {
      const int jl2 = t & 15;
      const int er = t >> 4;       // 0..31
      const float a0 = s_a[jl2][0], a1 = s_a[jl2][1];
      const float a2 = s_a[jl2][2], a3 = s_a[jl2][3];
      const int jj = jt * 16 + jl2;
#pragma unroll
      for (int k = 0; k < 8; ++k) {
        const int e = er + 32 * k;
        const size_t idxS = ((size_t)(b * 256 + e)) * 512 + 256 + jj;
        const size_t idxO = ((size_t)(b * 256 + e)) * 256 + jj;
        out0[idxS] = a0 * state[idxS] + a1 * o0[idxO] + a2 * o1[idxO] + a3 * o2[idxO];
      }
    }

    // ---- phase 3: out1 rows q = 256+j (4 sparse values, rest zero)
    {
      const int r = t >> 5;        // 0..15 (row within tile)
      const int c = t & 31;
      const int j3 = jt * 16 + r;
      const int q = 256 + j3;
      const int comp = j3 & 3;
      const int tc0 = (256 + j3) >> 2, tc1 = (512 + j3) >> 2;
      const int tc2 = (768 + j3) >> 2, tc3 = (1024 + j3) >> 2;
      const float av0 = s_a[r][0], av1 = s_a[r][1];
      const float av2 = s_a[r][2], av3 = s_a[r][3];
      float4* orow = (float4*)(out1 + ((size_t)(b * 512 + q)) * 1280);
#pragma unroll
      for (int k = 0; k < 10; ++k) {
        const int c4 = c + 32 * k;
        float4 o = make_float4(0.f, 0.f, 0.f, 0.f);
        float val = 0.f; bool hit = false;
        if (c4 == tc0)      { val = av0; hit = true; }
        else if (c4 == tc1) { val = av1; hit = true; }
        else if (c4 == tc2) { val = av2; hit = true; }
        else if (c4 == tc3) { val = av3; hit = true; }
        if (hit) {
          if (comp == 0) o.x = val; else if (comp == 1) o.y = val;
          else if (comp == 2) o.z = val; else o.w = val;
        }
        orow[c4] = o;
      }
    }
  } else if (blk < 1536) {
    // ================= role B: out0[b][e][0:256] = state copy ===========
    const int i2 = blk - 512;      // 0..1023
    const int b = i2 >> 5, eg = i2 & 31;
    const int row = t >> 6;        // 0..7
    const int col = (t & 63) << 2;
    const int e = eg * 8 + row;
    const size_t base = ((size_t)(b * 256 + e)) * 512 + col;
    *(float4*)(out0 + base) = *(const float4*)(state + base);
  } else {
    // ================= role C: out1 one-hot rows q < 256 ================
    const int i3 = blk - 1536;     // 0..1023
    const int b = i3 >> 5, qg = i3 & 31;
    if (t < 320) {
#pragma unroll
      for (int k = 0; k < 8; ++k) {
        const int q = qg * 8 + k;
        float4 o = make_float4(0.f, 0.f, 0.f, 0.f);
        if ((q >> 2) == t) {
          const int comp = q & 3;
          if (comp == 0) o.x = 1.f; else if (comp == 1) o.y = 1.f;
          else if (comp == 2) o.z = 1.f; else o.w = 1.f;
        }
        *(float4*)(out1 + ((size_t)(b * 512 + q)) * 1280 + t * 4) = o;
      }
    }
  }
}

extern "C" void kernel_launch(void* const* d_in, const int* in_sizes, int n_in,
                              void* d_out, int out_size, void* d_ws, size_t ws_size,
                              hipStream_t stream) {
  const float* state = (const float*)d_in[0];
  const float* obs0  = (const float*)d_in[1];
  const float* obs1  = (const float*)d_in[2];
  const float* obs2  = (const float*)d_in[3];
  const float* Q     = (const float*)d_in[4];
  const float* Wq    = (const float*)d_in[5];
  const float* bq    = (const float*)d_in[6];
  const float* Wk    = (const float*)d_in[7];
  // d_in[8] = bk: cancels in the 4-way softmax (shift invariance), unused.

  float* out0 = (float*)d_out;                       // new_state [32,256,512]
  float* out1 = out0 + (size_t)32 * 256 * 512;       // atten [32,512,1280]

  float* ws  = (float*)d_ws;
  float* u   = ws;              // 65536
  float* v   = u + 65536;       // 8192
  float* wu2 = v + 8192;        // 524288
  float* wv  = wu2 + 524288;    // 65536

  k_uv<<<288, 256, 0, stream>>>(Q, Wq, bq, u, v);
  k_w<<<dim3(256, 2), 256, 0, stream>>>(Wk, u, v, wu2, wv);
  k_mega<<<2560, 512, 0, stream>>>(state, obs0, obs1, obs2, wu2, wv, out0, out1);
}